// Round 12
// baseline (193.765 us; speedup 1.0000x reference)
//
#include <hip/hip_runtime.h>
#include <hip/hip_bf16.h>

#define BB 16
#define NQ 64
#define NK 512
#define HD 256   // H = QS = KS = VD = 256

typedef __attribute__((ext_vector_type(8))) short short8;
typedef __attribute__((ext_vector_type(4))) float f32x4;

__device__ __forceinline__ ushort bf16_rne(float v) {
    unsigned u = __float_as_uint(v);
    return (ushort)((u + 0x7FFFu + ((u >> 16) & 1u)) >> 16);
}
__device__ __forceinline__ float bf16_to_f(ushort h) {
    return __uint_as_float(((unsigned)h) << 16);
}

// ---------------------------------------------------------------------------
// K1: projection GEMM, fully fused conversions.  A fp32 -> hi/lo bf16 in
// registers -> XOR-swizzled LDS.  W fp32 [k][n] converted per block:
// thread <-> (n, k-chunk), 8 coalesced dword loads, pack short8, ONE
// ds_write_b128 into the same XOR-swizzled [n][chunk] layout (no u16
// scatter -- that was R4's bank-conflict poison).  C = AhWh+AlWh+AhWl.
// Tile 64x64, BK=64, grid (144,4).  Block (0,0) also zeroes the 128
// last-block-combine counters used by K2 (stream order guarantees K1 < K2).
// ---------------------------------------------------------------------------
__global__ __launch_bounds__(256, 2) void proj_all(
    const float* __restrict__ queries, const float* __restrict__ keys,
    const float* __restrict__ W_q, const float* __restrict__ W_k,
    float* __restrict__ qp, float* __restrict__ kp, float scale,
    int* __restrict__ cnt)
{
    if (blockIdx.x == 0 && blockIdx.y == 0 && threadIdx.x < 128)
        cnt[threadIdx.x] = 0;

    __shared__ ushort AsH[64 * 64], AsL[64 * 64];
    __shared__ ushort WtH[64 * 64], WtL[64 * 64];   // [n][8 chunks], swizzled

    const float* A; const float* W; float* C; int rows0;
    const int bx = blockIdx.x;
    if (bx < 16) { A = queries; W = W_q; C = qp; rows0 = bx * 64; }
    else         { A = keys;    W = W_k; C = kp; rows0 = (bx - 16) * 64; }
    const int cols0 = blockIdx.y * 64;

    const int t = threadIdx.x, lane = t & 63, wave = t >> 6;
    const int quad = lane >> 4, l15 = lane & 15;
    const int sr  = t >> 2;          // A staging row
    const int sc2 = (t & 3) * 2;     // A chunk pair
    const int wn  = t & 63;          // W staging: n within tile
    const int wkc = t >> 6;          // W k-chunk group base (0..3)

    f32x4 acc[4];
    #pragma unroll
    for (int j = 0; j < 4; ++j) acc[j] = (f32x4){0.f, 0.f, 0.f, 0.f};

    for (int k0 = 0; k0 < 256; k0 += 64) {
        // ---- global loads ----
        const float* arow = &A[(size_t)(rows0 + sr) * 256 + k0 + sc2 * 8];
        float4 a0 = *(const float4*)&arow[0];
        float4 a1 = *(const float4*)&arow[4];
        float4 a2 = *(const float4*)&arow[8];
        float4 a3 = *(const float4*)&arow[12];
        float wr[2][8];
        #pragma unroll
        for (int g = 0; g < 2; ++g) {
            const int kchunk = wkc + g * 4;
            #pragma unroll
            for (int j = 0; j < 8; ++j)
                wr[g][j] = W[(size_t)(k0 + kchunk * 8 + j) * 256 + cols0 + wn];
        }

        __syncthreads();   // previous tile's compute done

        // ---- A convert + swizzled store ----
        {
            float av[16] = {a0.x, a0.y, a0.z, a0.w, a1.x, a1.y, a1.z, a1.w,
                            a2.x, a2.y, a2.z, a2.w, a3.x, a3.y, a3.z, a3.w};
            short8 ah0, ah1, al0, al1;
            #pragma unroll
            for (int e = 0; e < 8; ++e) {
                ushort h0 = bf16_rne(av[e]);
                ushort h1 = bf16_rne(av[8 + e]);
                ah0[e] = (short)h0;
                ah1[e] = (short)h1;
                al0[e] = (short)bf16_rne(av[e] - bf16_to_f(h0));
                al1[e] = (short)bf16_rne(av[8 + e] - bf16_to_f(h1));
            }
            int s0 = sr * 8 + ((sc2 + 0) ^ (sr & 7));
            int s1 = sr * 8 + ((sc2 + 1) ^ (sr & 7));
            *(short8*)&AsH[s0 * 8] = ah0;
            *(short8*)&AsH[s1 * 8] = ah1;
            *(short8*)&AsL[s0 * 8] = al0;
            *(short8*)&AsL[s1 * 8] = al1;
        }
        // ---- W convert + swizzled transposed store ----
        #pragma unroll
        for (int g = 0; g < 2; ++g) {
            const int kchunk = wkc + g * 4;
            short8 h8, l8;
            #pragma unroll
            for (int j = 0; j < 8; ++j) {
                ushort h = bf16_rne(wr[g][j]);
                h8[j] = (short)h;
                l8[j] = (short)bf16_rne(wr[g][j] - bf16_to_f(h));
            }
            int slot = wn * 8 + (kchunk ^ (wn & 7));
            *(short8*)&WtH[slot * 8] = h8;
            *(short8*)&WtL[slot * 8] = l8;
        }
        __syncthreads();

        // ---- MFMA: 2 k32-steps, product-major ----
        #pragma unroll
        for (int ks = 0; ks < 2; ++ks) {
            const int c = ks * 4 + quad;
            short8 aH, aL, bH[4], bL[4];
            {
                int r = wave * 16 + l15;
                int slot = r * 8 + (c ^ (r & 7));
                aH = *(const short8*)&AsH[slot * 8];
                aL = *(const short8*)&AsL[slot * 8];
            }
            #pragma unroll
            for (int ns = 0; ns < 4; ++ns) {
                int n = ns * 16 + l15;
                int slot = n * 8 + (c ^ (n & 7));
                bH[ns] = *(const short8*)&WtH[slot * 8];
                bL[ns] = *(const short8*)&WtL[slot * 8];
            }
            #pragma unroll
            for (int ns = 0; ns < 4; ++ns)
                acc[ns] = __builtin_amdgcn_mfma_f32_16x16x32_bf16(aH, bH[ns], acc[ns], 0, 0, 0);
            #pragma unroll
            for (int ns = 0; ns < 4; ++ns)
                acc[ns] = __builtin_amdgcn_mfma_f32_16x16x32_bf16(aL, bH[ns], acc[ns], 0, 0, 0);
            #pragma unroll
            for (int ns = 0; ns < 4; ++ns)
                acc[ns] = __builtin_amdgcn_mfma_f32_16x16x32_bf16(aH, bL[ns], acc[ns], 0, 0, 0);
        }
    }

    const int rbase = rows0 + wave * 16 + quad * 4;
    #pragma unroll
    for (int ns = 0; ns < 4; ++ns) {
        int col = cols0 + ns * 16 + l15;
        #pragma unroll
        for (int r = 0; r < 4; ++r)
            C[(size_t)(rbase + r) * 256 + col] = acc[ns][r] * scale;
    }
}

// ---------------------------------------------------------------------------
// K2: segment flash partial + FUSED last-block combine.
// Block = (b, qtile of 8, 64-key segment), grid (128, 8), ~576 alive.
// Score/PV as R11 (eq=exp2(q) in LDS, ek shared by 8 q, batched loads).
// After writing partials: __threadfence + device atomicAdd on cnt[b*8+qt];
// the block seeing old == nc-1 re-fences and combines all <=8 segments.
// Masked keys -> s=-1e6 -> exp2 underflow to exact 0 (bit-exact skip).
// ---------------------------------------------------------------------------
__global__ __launch_bounds__(256) void score_pv_fused(
    const float* __restrict__ qp, const float* __restrict__ kp,
    const float* __restrict__ values, const int* __restrict__ vlens,
    const float* __restrict__ w_v,
    float* __restrict__ pO, float* __restrict__ pM, float* __restrict__ pL,
    int* __restrict__ cnt, float* __restrict__ out)
{
    __shared__ float eq[8][260];
    __shared__ float wv[HD];
    __shared__ float Ps[8][68];
    __shared__ int isLast;

    const int b   = blockIdx.x & 15;
    const int qt  = blockIdx.x >> 4;
    const int seg = blockIdx.y;
    const int vl  = vlens[b];
    if (seg * 64 >= vl) return;
    const int nc  = (vl + 63) >> 6;

    const int t = threadIdx.x, lane = t & 63, wave = t >> 6;

    const float* qsrc = qp + ((size_t)b * NQ + qt * 8) * HD;
    #pragma unroll
    for (int i = 0; i < 2; ++i) {
        int idx = i * 256 + t;
        int row = idx >> 6, c4 = (idx & 63) * 4;
        float4 v = *(const float4*)&qsrc[(size_t)row * HD + c4];
        eq[row][c4 + 0] = __builtin_amdgcn_exp2f(v.x);
        eq[row][c4 + 1] = __builtin_amdgcn_exp2f(v.y);
        eq[row][c4 + 2] = __builtin_amdgcn_exp2f(v.z);
        eq[row][c4 + 3] = __builtin_amdgcn_exp2f(v.w);
    }
    if (t < 64) *(float4*)&wv[t * 4] = *(const float4*)&w_v[t * 4];
    __syncthreads();

    float Wsum;
    {
        float ws = wv[lane] + wv[lane + 64] + wv[lane + 128] + wv[lane + 192];
        #pragma unroll
        for (int off = 32; off; off >>= 1) ws += __shfl_xor(ws, off);
        Wsum = ws;
    }

    // ---- scores ----
    const int key = wave * 16 + (lane >> 2);
    const int ch  = lane & 3;
    const int kg  = seg * 64 + key;
    const float* krow = kp + ((size_t)b * NK + kg) * HD + ch * 4;

    float s[8] = {0.f, 0.f, 0.f, 0.f, 0.f, 0.f, 0.f, 0.f};
    for (int j4 = 0; j4 < 4; ++j4) {
        float4 kk[4];
        #pragma unroll
        for (int u = 0; u < 4; ++u)
            kk[u] = *(const float4*)&krow[(j4 * 4 + u) * 16];
        #pragma unroll
        for (int u = 0; u < 4; ++u) {
            const int h = (j4 * 4 + u) * 16 + ch * 4;
            float4 w4 = *(const float4*)&wv[h];
            float ek0 = __builtin_amdgcn_exp2f(kk[u].x);
            float ek1 = __builtin_amdgcn_exp2f(kk[u].y);
            float ek2 = __builtin_amdgcn_exp2f(kk[u].z);
            float ek3 = __builtin_amdgcn_exp2f(kk[u].w);
            #pragma unroll
            for (int qi = 0; qi < 8; ++qi) {
                float4 q4 = *(const float4*)&eq[qi][h];
                float t0 = fmaf(w4.x, __builtin_amdgcn_rcpf(fmaf(q4.x, ek0, 1.f)), s[qi]);
                t0 = fmaf(w4.y, __builtin_amdgcn_rcpf(fmaf(q4.y, ek1, 1.f)), t0);
                t0 = fmaf(w4.z, __builtin_amdgcn_rcpf(fmaf(q4.z, ek2, 1.f)), t0);
                s[qi] = fmaf(w4.w, __builtin_amdgcn_rcpf(fmaf(q4.w, ek3, 1.f)), t0);
            }
        }
    }
    #pragma unroll
    for (int qi = 0; qi < 8; ++qi) {
        s[qi] += __shfl_xor(s[qi], 1);
        s[qi] += __shfl_xor(s[qi], 2);
    }
    if (ch == 0) {
        const bool masked = (kg >= vl);
        #pragma unroll
        for (int qi = 0; qi < 8; ++qi)
            Ps[qi][key] = masked ? -1e6f : fmaf(-2.f, s[qi], Wsum);
    }
    __syncthreads();

    // ---- per-segment softmax ----
    const float L2E = 1.4426950408889634f;
    #pragma unroll
    for (int r = 0; r < 2; ++r) {
        const int row = wave * 2 + r;
        float sv = Ps[row][lane];
        float m = sv;
        #pragma unroll
        for (int off = 32; off; off >>= 1) m = fmaxf(m, __shfl_xor(m, off));
        float e = __builtin_amdgcn_exp2f((sv - m) * L2E);
        float l = e;
        #pragma unroll
        for (int off = 32; off; off >>= 1) l += __shfl_xor(l, off);
        Ps[row][lane] = e;
        if (lane == 0) {
            size_t mi = (((size_t)(b * 8 + qt) * 8 + seg)) * 8 + row;
            pM[mi] = m;
            pL[mi] = l;
        }
    }
    __syncthreads();

    // ---- PV: wave owns rows {2w, 2w+1}, batched V loads ----
    const int r0 = wave * 2, r1 = r0 + 1;
    f32x4 acc0 = (f32x4){0.f, 0.f, 0.f, 0.f};
    f32x4 acc1 = (f32x4){0.f, 0.f, 0.f, 0.f};
    const float* vbase = values + ((size_t)b * NK + seg * 64) * HD;
    #pragma unroll 2
    for (int i0 = 0; i0 < 64; i0 += 4) {
        float4 v[4];
        #pragma unroll
        for (int u = 0; u < 4; ++u)
            v[u] = *(const float4*)&vbase[(size_t)(i0 + u) * HD + lane * 4];
        #pragma unroll
        for (int u = 0; u < 4; ++u) {
            float p0 = Ps[r0][i0 + u];
            float p1 = Ps[r1][i0 + u];
            acc0[0] = fmaf(p0, v[u].x, acc0[0]);
            acc0[1] = fmaf(p0, v[u].y, acc0[1]);
            acc0[2] = fmaf(p0, v[u].z, acc0[2]);
            acc0[3] = fmaf(p0, v[u].w, acc0[3]);
            acc1[0] = fmaf(p1, v[u].x, acc1[0]);
            acc1[1] = fmaf(p1, v[u].y, acc1[1]);
            acc1[2] = fmaf(p1, v[u].z, acc1[2]);
            acc1[3] = fmaf(p1, v[u].w, acc1[3]);
        }
    }
    const size_t ob = (((size_t)(b * 8 + qt) * 8 + seg)) * 8 * 256;
    *(f32x4*)&pO[ob + (size_t)r0 * 256 + lane * 4] = acc0;
    *(f32x4*)&pO[ob + (size_t)r1 * 256 + lane * 4] = acc1;

    // ---- last-block combine ----
    __threadfence();
    if (t == 0) {
        int old = atomicAdd(&cnt[b * 8 + qt], 1);
        isLast = (old == nc - 1) ? 1 : 0;
    }
    __syncthreads();
    if (!isLast) return;
    __threadfence();   // acquire: other blocks' partials now visible

    const size_t base = (size_t)(b * 8 + qt) * 8;   // + seg, then *8 + qi
    #pragma unroll
    for (int qi = 0; qi < 8; ++qi) {
        float mi[8], li[8];
        float m = -3e38f;
        #pragma unroll
        for (int i = 0; i < 8; ++i) {
            if (i < nc) {
                mi[i] = pM[(base + i) * 8 + qi];
                li[i] = pL[(base + i) * 8 + qi];
                m = fmaxf(m, mi[i]);
            }
        }
        float L = 0.f, wi[8];
        #pragma unroll
        for (int i = 0; i < 8; ++i) {
            if (i < nc) {
                wi[i] = __builtin_amdgcn_exp2f((mi[i] - m) * L2E);
                L = fmaf(li[i], wi[i], L);
            }
        }
        float acc = 0.f;
        #pragma unroll
        for (int i = 0; i < 8; ++i) {
            if (i < nc) acc = fmaf(wi[i], pO[((base + i) * 8 + qi) * 256 + t], acc);
        }
        out[((size_t)(b * 64 + qt * 8 + qi)) * 256 + t] = acc * __builtin_amdgcn_rcpf(L);
    }
}

extern "C" void kernel_launch(void* const* d_in, const int* in_sizes, int n_in,
                              void* d_out, int out_size, void* d_ws, size_t ws_size,
                              hipStream_t stream) {
    const float* queries = (const float*)d_in[0];
    const float* keys    = (const float*)d_in[1];
    const float* values  = (const float*)d_in[2];
    const int*   vlens   = (const int*)d_in[3];
    const float* W_q     = (const float*)d_in[4];
    const float* W_k     = (const float*)d_in[5];
    const float* w_v     = (const float*)d_in[6];
    float* out = (float*)d_out;

    // ws layout (~17.1 MB of 256 MiB):
    float* kp = (float*)d_ws;                          // 8 MB
    float* qp = kp + (size_t)BB * NK * HD;             // 1 MB
    float* pO = qp + (size_t)BB * NQ * HD;             // 8 MB
    float* pM = pO + (size_t)BB * 8 * 8 * 8 * 256;     // 32 KB
    float* pL = pM + (size_t)BB * 8 * 8 * 8;           // 32 KB
    int*   cnt = (int*)(pL + (size_t)BB * 8 * 8 * 8);  // 512 B (zeroed by K1)

    const float SC = 2.885390081777927f;               // 2/ln(2)

    proj_all<<<dim3(144, 4), 256, 0, stream>>>(queries, keys, W_q, W_k,
                                               qp, kp, SC, cnt);
    score_pv_fused<<<dim3(128, 8), 256, 0, stream>>>(qp, kp, values, vlens, w_v,
                                                     pO, pM, pL, cnt, out);
}

// Round 13
// 115.017 us; speedup vs baseline: 1.6847x; 1.6847x over previous
//
#include <hip/hip_runtime.h>
#include <hip/hip_bf16.h>

#define BB 16
#define NQ 64
#define NK 512
#define HD 256   // H = QS = KS = VD = 256

typedef __attribute__((ext_vector_type(8))) short short8;
typedef __attribute__((ext_vector_type(4))) float f32x4;

__device__ __forceinline__ ushort bf16_rne(float v) {
    unsigned u = __float_as_uint(v);
    return (ushort)((u + 0x7FFFu + ((u >> 16) & 1u)) >> 16);
}
__device__ __forceinline__ float bf16_to_f(ushort h) {
    return __uint_as_float(((unsigned)h) << 16);
}

// ---------------------------------------------------------------------------
// K1: projection GEMM, fused conversions, 512 threads (8 waves) for latency
// hiding.  Tile 64x64, BK=64, grid (144,4) = 576 blocks (~2.25/CU -> ~18
// waves/CU).  A fp32 -> hi/lo bf16 in regs -> XOR-swizzled LDS (1 chunk per
// thread); W fp32 [k][n]: thread=(kchunk=t>>6, n=t&63), 8 coalesced dword
// loads, ONE swizzled ds_write_b128 (no u16 scatter).  C = AhWh+AlWh+AhWl.
// MFMA: wave (mw=w&3, nw=w>>2) owns 16 rows x 32 cols = 2 subtiles.
// ---------------------------------------------------------------------------
__global__ __launch_bounds__(512, 4) void proj_all(
    const float* __restrict__ queries, const float* __restrict__ keys,
    const float* __restrict__ W_q, const float* __restrict__ W_k,
    float* __restrict__ qp, float* __restrict__ kp, float scale)
{
    __shared__ ushort AsH[64 * 64], AsL[64 * 64];
    __shared__ ushort WtH[64 * 64], WtL[64 * 64];

    const float* A; const float* W; float* C; int rows0;
    const int bx = blockIdx.x;
    if (bx < 16) { A = queries; W = W_q; C = qp; rows0 = bx * 64; }
    else         { A = keys;    W = W_k; C = kp; rows0 = (bx - 16) * 64; }
    const int cols0 = blockIdx.y * 64;

    const int t = threadIdx.x, lane = t & 63, wave = t >> 6;
    const int quad = lane >> 4, l15 = lane & 15;
    const int sr = t >> 3, sc = t & 7;       // A staging: row 0..63, chunk 0..7
    const int wn = t & 63, wkc = t >> 6;     // W staging: n, kchunk 0..7
    const int mw = wave & 3, nw = wave >> 2; // MFMA wave tile

    f32x4 acc[2];
    acc[0] = (f32x4){0.f, 0.f, 0.f, 0.f};
    acc[1] = (f32x4){0.f, 0.f, 0.f, 0.f};

    for (int k0 = 0; k0 < 256; k0 += 64) {
        // ---- global loads (1 A-chunk + 8 W dwords per thread) ----
        const float* arow = &A[(size_t)(rows0 + sr) * 256 + k0 + sc * 8];
        float4 a0 = *(const float4*)&arow[0];
        float4 a1 = *(const float4*)&arow[4];
        float wr[8];
        #pragma unroll
        for (int j = 0; j < 8; ++j)
            wr[j] = W[(size_t)(k0 + wkc * 8 + j) * 256 + cols0 + wn];

        __syncthreads();   // previous tile's compute done

        // ---- A convert + swizzled store ----
        {
            float av[8] = {a0.x, a0.y, a0.z, a0.w, a1.x, a1.y, a1.z, a1.w};
            short8 ah, al;
            #pragma unroll
            for (int e = 0; e < 8; ++e) {
                ushort h = bf16_rne(av[e]);
                ah[e] = (short)h;
                al[e] = (short)bf16_rne(av[e] - bf16_to_f(h));
            }
            int slot = sr * 8 + (sc ^ (sr & 7));
            *(short8*)&AsH[slot * 8] = ah;
            *(short8*)&AsL[slot * 8] = al;
        }
        // ---- W convert + swizzled transposed store ----
        {
            short8 h8, l8;
            #pragma unroll
            for (int j = 0; j < 8; ++j) {
                ushort h = bf16_rne(wr[j]);
                h8[j] = (short)h;
                l8[j] = (short)bf16_rne(wr[j] - bf16_to_f(h));
            }
            int slot = wn * 8 + (wkc ^ (wn & 7));
            *(short8*)&WtH[slot * 8] = h8;
            *(short8*)&WtL[slot * 8] = l8;
        }
        __syncthreads();

        // ---- MFMA: 2 k32-steps, 2 n-subtiles, product-major ----
        #pragma unroll
        for (int ks = 0; ks < 2; ++ks) {
            const int c = ks * 4 + quad;
            short8 aH, aL, bH[2], bL[2];
            {
                int r = mw * 16 + l15;
                int slot = r * 8 + (c ^ (r & 7));
                aH = *(const short8*)&AsH[slot * 8];
                aL = *(const short8*)&AsL[slot * 8];
            }
            #pragma unroll
            for (int ns = 0; ns < 2; ++ns) {
                int n = nw * 32 + ns * 16 + l15;
                int slot = n * 8 + (c ^ (n & 7));
                bH[ns] = *(const short8*)&WtH[slot * 8];
                bL[ns] = *(const short8*)&WtL[slot * 8];
            }
            #pragma unroll
            for (int ns = 0; ns < 2; ++ns)
                acc[ns] = __builtin_amdgcn_mfma_f32_16x16x32_bf16(aH, bH[ns], acc[ns], 0, 0, 0);
            #pragma unroll
            for (int ns = 0; ns < 2; ++ns)
                acc[ns] = __builtin_amdgcn_mfma_f32_16x16x32_bf16(aL, bH[ns], acc[ns], 0, 0, 0);
            #pragma unroll
            for (int ns = 0; ns < 2; ++ns)
                acc[ns] = __builtin_amdgcn_mfma_f32_16x16x32_bf16(aH, bL[ns], acc[ns], 0, 0, 0);
        }
    }

    const int rbase = rows0 + mw * 16 + quad * 4;
    #pragma unroll
    for (int ns = 0; ns < 2; ++ns) {
        int col = cols0 + nw * 32 + ns * 16 + l15;
        #pragma unroll
        for (int r = 0; r < 4; ++r)
            C[(size_t)(rbase + r) * 256 + col] = acc[ns][r] * scale;
    }
}

// ---------------------------------------------------------------------------
// K2: segment flash partial, 512 threads (8 waves).  Block = (b, qtile of 8,
// 64-key segment), grid (128,8), ~576 alive, ~20 KB LDS.
// Score: lane=(key=wave*8+(lane>>3), ch=lane&7); all 8 k-float4s loaded
// upfront (MLP=8).  eq=exp2(q) in LDS; ek=exp2(k) shared by 8 queries.
// Softmax: wave w owns q-row w.  PV: wave w owns rows {2(w&3), 2(w&3)+1}
// for keys [(w>>2)*32, +32); cross-wave-pair LDS reduce (NO fences/atomics
// — R12 showed device-scope fences are catastrophic on multi-XCD).
// Masked keys -> s=-1e6 -> exp2 underflow to exact 0 (bit-exact skip).
// ---------------------------------------------------------------------------
__global__ __launch_bounds__(512, 4) void score_pv_seg4(
    const float* __restrict__ qp,      // [B*NQ, H] pre-scaled by 2/ln2
    const float* __restrict__ kp,      // [B*NK, H] pre-scaled
    const float* __restrict__ values,  // [B, NK, VD]
    const int*   __restrict__ vlens,   // [B]
    const float* __restrict__ w_v,     // [H]
    float* __restrict__ pO,            // [B][8qt][8seg][8q][256]
    float* __restrict__ pM,            // [B][8qt][8seg][8q]
    float* __restrict__ pL)            // [B][8qt][8seg][8q]
{
    __shared__ float eq[8][260];
    __shared__ float wv[HD];
    __shared__ float Ps[8][68];
    __shared__ float part[4][2][260];

    const int b   = blockIdx.x & 15;
    const int qt  = blockIdx.x >> 4;
    const int seg = blockIdx.y;
    const int vl  = vlens[b];
    if (seg * 64 >= vl) return;

    const int t = threadIdx.x, lane = t & 63, wave = t >> 6;

    // stage eq = exp2(q): 512 float4s, one per thread
    const float* qsrc = qp + ((size_t)b * NQ + qt * 8) * HD;
    {
        int row = t >> 6, c4 = (t & 63) * 4;
        float4 v = *(const float4*)&qsrc[(size_t)row * HD + c4];
        eq[row][c4 + 0] = __builtin_amdgcn_exp2f(v.x);
        eq[row][c4 + 1] = __builtin_amdgcn_exp2f(v.y);
        eq[row][c4 + 2] = __builtin_amdgcn_exp2f(v.z);
        eq[row][c4 + 3] = __builtin_amdgcn_exp2f(v.w);
    }
    if (t < 64) *(float4*)&wv[t * 4] = *(const float4*)&w_v[t * 4];
    __syncthreads();

    float Wsum;
    {
        float ws = wv[lane] + wv[lane + 64] + wv[lane + 128] + wv[lane + 192];
        #pragma unroll
        for (int off = 32; off; off >>= 1) ws += __shfl_xor(ws, off);
        Wsum = ws;
    }

    // ---- scores: 8 keys/wave, 8 h-chunks/key, MLP=8 ----
    const int key = wave * 8 + (lane >> 3);
    const int ch  = lane & 7;
    const int kg  = seg * 64 + key;
    const float* krow = kp + ((size_t)b * NK + kg) * HD + ch * 4;

    float4 kk[8];
    #pragma unroll
    for (int j = 0; j < 8; ++j) kk[j] = *(const float4*)&krow[j * 32];

    float s[8] = {0.f, 0.f, 0.f, 0.f, 0.f, 0.f, 0.f, 0.f};
    #pragma unroll
    for (int j = 0; j < 8; ++j) {
        const int h = j * 32 + ch * 4;
        float4 w4 = *(const float4*)&wv[h];
        float ek0 = __builtin_amdgcn_exp2f(kk[j].x);
        float ek1 = __builtin_amdgcn_exp2f(kk[j].y);
        float ek2 = __builtin_amdgcn_exp2f(kk[j].z);
        float ek3 = __builtin_amdgcn_exp2f(kk[j].w);
        #pragma unroll
        for (int qi = 0; qi < 8; ++qi) {
            float4 q4 = *(const float4*)&eq[qi][h];   // LDS broadcast
            float t0 = fmaf(w4.x, __builtin_amdgcn_rcpf(fmaf(q4.x, ek0, 1.f)), s[qi]);
            t0 = fmaf(w4.y, __builtin_amdgcn_rcpf(fmaf(q4.y, ek1, 1.f)), t0);
            t0 = fmaf(w4.z, __builtin_amdgcn_rcpf(fmaf(q4.z, ek2, 1.f)), t0);
            s[qi] = fmaf(w4.w, __builtin_amdgcn_rcpf(fmaf(q4.w, ek3, 1.f)), t0);
        }
    }
    #pragma unroll
    for (int qi = 0; qi < 8; ++qi) {
        s[qi] += __shfl_xor(s[qi], 1);
        s[qi] += __shfl_xor(s[qi], 2);
        s[qi] += __shfl_xor(s[qi], 4);
    }
    if (ch == 0) {
        const bool masked = (kg >= vl);
        #pragma unroll
        for (int qi = 0; qi < 8; ++qi)
            Ps[qi][key] = masked ? -1e6f : fmaf(-2.f, s[qi], Wsum);
    }
    __syncthreads();

    // ---- per-segment softmax: wave w owns q-row w ----
    const float L2E = 1.4426950408889634f;
    {
        float sv = Ps[wave][lane];
        float m = sv;
        #pragma unroll
        for (int off = 32; off; off >>= 1) m = fmaxf(m, __shfl_xor(m, off));
        float e = __builtin_amdgcn_exp2f((sv - m) * L2E);
        float l = e;
        #pragma unroll
        for (int off = 32; off; off >>= 1) l += __shfl_xor(l, off);
        Ps[wave][lane] = e;
        if (lane == 0) {
            size_t mi = (((size_t)(b * 8 + qt) * 8 + seg)) * 8 + wave;
            pM[mi] = m;
            pL[mi] = l;
        }
    }
    __syncthreads();

    // ---- PV: wave -> rows {2(w&3), 2(w&3)+1}, keys [(w>>2)*32, +32) ----
    const int r0 = (wave & 3) * 2, r1 = r0 + 1;
    const int kb = (wave >> 2) * 32;
    f32x4 acc0 = (f32x4){0.f, 0.f, 0.f, 0.f};
    f32x4 acc1 = (f32x4){0.f, 0.f, 0.f, 0.f};
    const float* vbase = values + ((size_t)b * NK + seg * 64 + kb) * HD;
    #pragma unroll 2
    for (int i0 = 0; i0 < 32; i0 += 4) {
        float4 v[4];
        #pragma unroll
        for (int u = 0; u < 4; ++u)
            v[u] = *(const float4*)&vbase[(size_t)(i0 + u) * HD + lane * 4];
        #pragma unroll
        for (int u = 0; u < 4; ++u) {
            float p0 = Ps[r0][kb + i0 + u];
            float p1 = Ps[r1][kb + i0 + u];
            acc0[0] = fmaf(p0, v[u].x, acc0[0]);
            acc0[1] = fmaf(p0, v[u].y, acc0[1]);
            acc0[2] = fmaf(p0, v[u].z, acc0[2]);
            acc0[3] = fmaf(p0, v[u].w, acc0[3]);
            acc1[0] = fmaf(p1, v[u].x, acc1[0]);
            acc1[1] = fmaf(p1, v[u].y, acc1[1]);
            acc1[2] = fmaf(p1, v[u].z, acc1[2]);
            acc1[3] = fmaf(p1, v[u].w, acc1[3]);
        }
    }
    // waves 4-7 (keys 32-63) park partials in LDS; waves 0-3 finish
    if (wave >= 4) {
        *(f32x4*)&part[wave - 4][0][lane * 4] = acc0;
        *(f32x4*)&part[wave - 4][1][lane * 4] = acc1;
    }
    __syncthreads();
    if (wave < 4) {
        float4 q0 = *(const float4*)&part[wave][0][lane * 4];
        float4 q1 = *(const float4*)&part[wave][1][lane * 4];
        acc0[0] += q0.x; acc0[1] += q0.y; acc0[2] += q0.z; acc0[3] += q0.w;
        acc1[0] += q1.x; acc1[1] += q1.y; acc1[2] += q1.z; acc1[3] += q1.w;
        const size_t ob = (((size_t)(b * 8 + qt) * 8 + seg)) * 8 * 256;
        *(f32x4*)&pO[ob + (size_t)r0 * 256 + lane * 4] = acc0;
        *(f32x4*)&pO[ob + (size_t)r1 * 256 + lane * 4] = acc1;
    }
}

// ---------------------------------------------------------------------------
// K3: combine, block per (b,q), 256 threads (one vd element each).
// ---------------------------------------------------------------------------
__global__ __launch_bounds__(256) void combine_seg2(
    const float* __restrict__ pO, const float* __restrict__ pM,
    const float* __restrict__ pL, const int* __restrict__ vlens,
    float* __restrict__ out)
{
    const int b  = blockIdx.x >> 6;
    const int q  = blockIdx.x & 63;
    const int t  = threadIdx.x;
    const int vl = vlens[b];
    const int nc = (vl + 63) >> 6;
    const int qt = q >> 3, qi = q & 7;
    const float L2E = 1.4426950408889634f;

    const size_t base = (size_t)(b * 8 + qt) * 8;

    float mi[8], li[8];
    float m = -3e38f;
    #pragma unroll
    for (int i = 0; i < 8; ++i) {
        if (i < nc) {
            mi[i] = pM[(base + i) * 8 + qi];
            li[i] = pL[(base + i) * 8 + qi];
            m = fmaxf(m, mi[i]);
        }
    }
    float L = 0.f, wi[8];
    #pragma unroll
    for (int i = 0; i < 8; ++i) {
        if (i < nc) {
            wi[i] = __builtin_amdgcn_exp2f((mi[i] - m) * L2E);
            L = fmaf(li[i], wi[i], L);
        }
    }
    float acc = 0.f;
    #pragma unroll
    for (int i = 0; i < 8; ++i) {
        if (i < nc) acc = fmaf(wi[i], pO[((base + i) * 8 + qi) * 256 + t], acc);
    }
    out[((size_t)(b * 64 + q)) * 256 + t] = acc * __builtin_amdgcn_rcpf(L);
}

extern "C" void kernel_launch(void* const* d_in, const int* in_sizes, int n_in,
                              void* d_out, int out_size, void* d_ws, size_t ws_size,
                              hipStream_t stream) {
    const float* queries = (const float*)d_in[0];
    const float* keys    = (const float*)d_in[1];
    const float* values  = (const float*)d_in[2];
    const int*   vlens   = (const int*)d_in[3];
    const float* W_q     = (const float*)d_in[4];
    const float* W_k     = (const float*)d_in[5];
    const float* w_v     = (const float*)d_in[6];
    float* out = (float*)d_out;

    // ws layout (~17.1 MB of 256 MiB):
    float* kp = (float*)d_ws;                          // 8 MB
    float* qp = kp + (size_t)BB * NK * HD;             // 1 MB
    float* pO = qp + (size_t)BB * NQ * HD;             // 8 MB
    float* pM = pO + (size_t)BB * 8 * 8 * 8 * 256;     // 32 KB
    float* pL = pM + (size_t)BB * 8 * 8 * 8;           // 32 KB

    const float SC = 2.885390081777927f;               // 2/ln(2)

    proj_all<<<dim3(144, 4), 512, 0, stream>>>(queries, keys, W_q, W_k,
                                               qp, kp, SC);
    score_pv_seg4<<<dim3(128, 8), 512, 0, stream>>>(qp, kp, values, vlens, w_v,
                                                    pO, pM, pL);
    combine_seg2<<<dim3(BB * NQ), 256, 0, stream>>>(pO, pM, pL, vlens, out);
}